// Round 4
// baseline (184.375 us; speedup 1.0000x reference)
//
#include <hip/hip_runtime.h>
#include <hip/hip_bf16.h>
#include <math.h>

#define NN 4096
#define NC 128
#define NH 8
#define NV 16
#define NB 4
#define BD 64   // NB*NV

typedef _Float16 half8 __attribute__((ext_vector_type(8)));
typedef __fp16  fp16x2 __attribute__((ext_vector_type(2)));
typedef float floatx4 __attribute__((ext_vector_type(4)));

__device__ __forceinline__ int get_loc(const int* locp){
    int lr = locp[0];
    return (lr >= 0 && lr <= 100) ? lr : 64;
}
__device__ __forceinline__ float head_scale(const float* rr, int h){
    float ts = tanf(0.78539816339744831f * (1.0f + sinf(rr[h])));
    if (!(ts > 0.f)) ts = (ts == 0.f) ? 1e-20f : 1e20f;
    if (ts > 1e20f) ts = 1e20f;
    return ts;
}
// barrier that drains LDS only — leaves global loads (vmcnt) in flight.
__device__ __forceinline__ void lds_barrier(){
    __asm__ __volatile__("s_waitcnt lgkmcnt(0)\n\ts_barrier" ::: "memory");
}

// ---------------------------------------------------------------------------
// K1: per row i of dist (f32 in [0,1)): Kval_i = rank-th smallest
// (rank = floor(loc*(N-1)/100)+1), xmin_i = row min.  (unchanged)
// ---------------------------------------------------------------------------
__global__ __launch_bounds__(256) void k_rowstats(const float* __restrict__ dist,
                                                  const int* __restrict__ locp,
                                                  float* __restrict__ Kval,
                                                  float* __restrict__ xminp){
    __shared__ unsigned int hist[4][256];
    __shared__ float cand[1024];
    __shared__ unsigned int cnt, selb_s, basec_s, xminu;
    const int i = blockIdx.x, t = threadIdx.x;
    const int wv = t >> 6, lane = t & 63;
    const int loc = get_loc(locp);
    const unsigned int rank = (unsigned int)(((long long)loc * (NN - 1)) / 100) + 1u;

    float v[16];
    const float4* rp = (const float4*)(dist + (size_t)i * NN);
#pragma unroll
    for (int k = 0; k < 4; k++){
        float4 x4 = rp[k * 256 + t];
        v[4*k+0] = x4.x; v[4*k+1] = x4.y; v[4*k+2] = x4.z; v[4*k+3] = x4.w;
    }
    for (int k = t; k < 1024; k += 256) ((unsigned int*)hist)[k] = 0;
    if (t == 0){ cnt = 0; selb_s = 255u; basec_s = 0u; xminu = 0xFFFFFFFFu; }
    __syncthreads();

    float lmin = 1e30f;
#pragma unroll
    for (int u = 0; u < 16; u++){
        float x = v[u];
        lmin = fminf(lmin, x);
        int b = (int)(x * 256.0f); b = b < 0 ? 0 : (b > 255 ? 255 : b);
        atomicAdd(&hist[wv][b], 1u);
    }
#pragma unroll
    for (int off = 1; off < 64; off <<= 1) lmin = fminf(lmin, __shfl_xor(lmin, off));
    if (lane == 0) atomicMin(&xminu, __float_as_uint(lmin));
    __syncthreads();

    if (t < 64){
        unsigned int lp[4];
        unsigned int run = 0;
#pragma unroll
        for (int q = 0; q < 4; q++){
            int b = 4 * t + q;
            run += hist[0][b] + hist[1][b] + hist[2][b] + hist[3][b];
            lp[q] = run;
        }
        unsigned int incl = run;
#pragma unroll
        for (int d = 1; d < 64; d <<= 1){
            unsigned int y = __shfl_up(incl, d);
            if (t >= d) incl += y;
        }
        unsigned int excl = incl - run;
        if (excl < rank && rank <= incl){
#pragma unroll
            for (int q = 0; q < 4; q++){
                if (excl + lp[q] >= rank){
                    selb_s  = (unsigned int)(4 * t + q);
                    basec_s = excl + (q ? lp[q-1] : 0u);
                    break;
                }
            }
        }
    }
    __syncthreads();
    const unsigned int sb = selb_s;
    if (t == 0) Kval[i] = ((float)sb + 1.0f) * 0.00390625f;   // fallback, overwritten below
#pragma unroll
    for (int u = 0; u < 16; u++){
        float x = v[u];
        int b = (int)(x * 256.0f); b = b < 0 ? 0 : (b > 255 ? 255 : b);
        if ((unsigned int)b == sb){
            unsigned int idx = atomicAdd(&cnt, 1u);
            if (idx < 1024u) cand[idx] = x;
        }
    }
    __syncthreads();
    const unsigned int n = cnt > 1024u ? 1024u : cnt;
    const unsigned int need = rank - basec_s;
    for (unsigned int c0 = t; c0 < n; c0 += 256){
        float x = cand[c0];
        unsigned int lt = 0, le = 0;
        for (unsigned int k2 = 0; k2 < n; k2++){
            float y = cand[k2];
            lt += (y < x); le += (y <= x);
        }
        if (lt < need && need <= le) Kval[i] = x;
    }
    if (t == 0) xminp[i] = __uint_as_float(xminu);
}

// ---------------------------------------------------------------------------
// K2 (MFMA rewrite): val_t[h][bd][j] = sum_c in[b][j][c]*wgt[h][c][v],
// bd = b*16+v.  GEMM per batch: A = in (m=j, k=c, f16 hi/lo compensated
// split -> ~f32 accuracy), B = wgt-f16 staged [hv][c] in LDS, frags held
// in registers.  D layout: m=(lane>>4)*4+reg (j), n=lane&15 (hv) -> 4
// consecutive-j f16 per lane = one 8B store.
// ---------------------------------------------------------------------------
__global__ __launch_bounds__(256) void k_value(const float* __restrict__ in,
                                               const float* __restrict__ wgt,
                                               _Float16* __restrict__ val_t){
    __shared__ _Float16 Wt[NH * NV * 136];      // [hv][c] pad->136: 2-way banks
    const int b  = blockIdx.y;
    const int j0 = blockIdx.x * 32;
    const int t  = threadIdx.x, lane = t & 63, wv = t >> 6;

    // stage wgt -> f16 transposed: coalesced global reads, scattered LDS writes
    for (int w = t; w < NH * NC * NV; w += 256){
        int h = w >> 11, c = (w >> 4) & 127, v = w & 15;
        Wt[(h * 16 + v) * 136 + c] = (_Float16)wgt[w];
    }
    __syncthreads();

    const int kl = (lane >> 4) * 8;             // k-offset inside a K=32 chunk
    half8 Bf[2][4];
#pragma unroll
    for (int nt = 0; nt < 2; nt++){
        const int hv = wv * 32 + nt * 16 + (lane & 15);
#pragma unroll
        for (int kc = 0; kc < 4; kc++)
            Bf[nt][kc] = *(const half8*)&Wt[hv * 136 + kc * 32 + kl];
    }

    floatx4 acc[2][2];
#pragma unroll
    for (int a = 0; a < 2; a++)
#pragma unroll
        for (int c = 0; c < 2; c++) acc[a][c] = (floatx4){0.f,0.f,0.f,0.f};

    const float* ip = in + ((size_t)b * NN + j0 + (lane & 15)) * NC + kl;
#pragma unroll
    for (int jm = 0; jm < 2; jm++){
        const float* ipm = ip + jm * 16 * NC;
#pragma unroll
        for (int kc = 0; kc < 4; kc++){
            float4 x0 = *(const float4*)(ipm + kc * 32);
            float4 x1 = *(const float4*)(ipm + kc * 32 + 4);
            const float xs[8] = {x0.x,x0.y,x0.z,x0.w,x1.x,x1.y,x1.z,x1.w};
            union { half8 h8; fp16x2 h2[4]; } hi, lo;
#pragma unroll
            for (int u = 0; u < 4; u++){
                hi.h2[u] = __builtin_amdgcn_cvt_pkrtz(xs[2*u], xs[2*u+1]);
                float r0 = xs[2*u]   - (float)hi.h2[u][0];
                float r1 = xs[2*u+1] - (float)hi.h2[u][1];
                lo.h2[u] = __builtin_amdgcn_cvt_pkrtz(r0, r1);
            }
#pragma unroll
            for (int nt = 0; nt < 2; nt++){
                acc[jm][nt] = __builtin_amdgcn_mfma_f32_16x16x32_f16(hi.h8, Bf[nt][kc], acc[jm][nt], 0, 0, 0);
                acc[jm][nt] = __builtin_amdgcn_mfma_f32_16x16x32_f16(lo.h8, Bf[nt][kc], acc[jm][nt], 0, 0, 0);
            }
        }
    }

    const int jw = (lane >> 4) * 4;
#pragma unroll
    for (int jm = 0; jm < 2; jm++)
#pragma unroll
        for (int nt = 0; nt < 2; nt++){
            const int hv  = wv * 32 + nt * 16 + (lane & 15);
            const int row = (hv >> 4) * BD + b * NV + (hv & 15);
            union { _Float16 h[4]; uint2 u; } o;
#pragma unroll
            for (int u = 0; u < 4; u++) o.h[u] = (_Float16)acc[jm][nt][u];
            *(uint2*)&val_t[(size_t)row * NN + j0 + jm * 16 + jw] = o.u;
        }
}

// ---------------------------------------------------------------------------
// K3 (MFMA): 64-i tiles, grid (NN/64, NH) = 512 blocks, 4 waves.
// Wave wv owns i-rows [i0+wv*16, +16) x all 64 bd -> A rows wave-unique.
// A (softmax weights) computed DIRECTLY IN REGISTERS from dist loads (no
// wtile LDS round-trip).  Only vtile stays in LDS (double-buffered, one
// lgkm-barrier per 64-j tile).
// ---------------------------------------------------------------------------
__global__ __launch_bounds__(256) void k_att(const float* __restrict__ dist,
                                             const float* __restrict__ rr,
                                             const _Float16* __restrict__ val_t,
                                             const float* __restrict__ Kvalp,
                                             const float* __restrict__ xminp,
                                             float* __restrict__ out){
    __shared__ alignas(16) _Float16 vtile[2][64 * 72];   // [bd][j] 2 x 9 KB

    // XCD remap: 512 blocks, h fastest within an XCD -> the 8 h-blocks of an
    // i-tile are temporally adjacent and share dist rows via L2.
    const int l   = blockIdx.x + (NN / 64) * blockIdx.y;   // 0..511
    const int xcd = l & 7;
    const int s   = l >> 3;                                // 0..63
    const int i0  = (xcd * 8 + (s >> 3)) * 64;
    const int h   = s & 7;

    const int t = threadIdx.x, lane = t & 63, wv = t >> 6;
    const float ts   = head_scale(rr, h);
    const float ts2  = ts * 1.44269504088896f;  // exp(a) = exp2(a*log2e)
    const float nts2 = -ts2;

    const int irow = i0 + wv * 16 + (lane & 15);   // this lane's A row (global i)
    const float kvi  = Kvalp[irow];
    const float txmi = ts2 * xminp[irow];

    // v staging role
    const int vrow = t >> 3, vpart = t & 7;
    const _Float16* vp0 = val_t + (size_t)(h * BD + vrow) * NN + vpart * 8;
    const _Float16* vp1 = vp0 + (size_t)32 * NN;
    const int voff0 = vrow * 72 + vpart * 8;
    const int voff1 = (vrow + 32) * 72 + vpart * 8;

    const int kl = (lane >> 4) * 8;                // j-offset inside K=32 chunk
    const float* dp = dist + (size_t)irow * NN + kl;

    const int bbase = (lane & 15) * 72 + kl;       // + nt*16*72 + kc*32

    half8 ones;
#pragma unroll
    for (int u = 0; u < 8; u++) ones[u] = (_Float16)1.0f;

    floatx4 acc[4];
#pragma unroll
    for (int nt = 0; nt < 4; nt++) acc[nt] = (floatx4){0.f,0.f,0.f,0.f};
    floatx4 accs = (floatx4){0.f,0.f,0.f,0.f};

    uint4  Av0, Av1, Bv0, Bv1;
    float4 Ad[4], Bd[4];
    half8  WA[2], WB[2];

#define LOADD(D) do{                                                         \
        D[0] = *(const float4*)dp;        D[1] = *(const float4*)(dp + 4);   \
        D[2] = *(const float4*)(dp + 32); D[3] = *(const float4*)(dp + 36);  \
        dp += 64; }while(0)

#define LOADV(V0, V1) do{                                                    \
        V0 = *(const uint4*)vp0;  vp0 += 64;                                 \
        V1 = *(const uint4*)vp1;  vp1 += 64; }while(0)

#define STAGEV(BUF, V0, V1) do{                                              \
        *(uint4*)&vtile[BUF][voff0] = V0;                                    \
        *(uint4*)&vtile[BUF][voff1] = V1; }while(0)

// dist regs -> masked exp2 weights, packed f16, kept in registers (A-frag)
#define WCOMP(W, D) do{                                                      \
        _Pragma("unroll")                                                    \
        for (int kc_ = 0; kc_ < 2; kc_++){                                   \
            const float dd_[8] = {D[2*kc_].x, D[2*kc_].y, D[2*kc_].z, D[2*kc_].w, \
                                  D[2*kc_+1].x, D[2*kc_+1].y, D[2*kc_+1].z, D[2*kc_+1].w}; \
            union { half8 h8; fp16x2 h2[4]; } uu_;                           \
            _Pragma("unroll")                                                \
            for (int u_ = 0; u_ < 4; u_++){                                  \
                float a0_ = fmaf(nts2, dd_[2*u_  ], txmi);                   \
                float a1_ = fmaf(nts2, dd_[2*u_+1], txmi);                   \
                a0_ = (dd_[2*u_  ] <= kvi) ? a0_ : -20000.0f;                \
                a1_ = (dd_[2*u_+1] <= kvi) ? a1_ : -20000.0f;                \
                uu_.h2[u_] = __builtin_amdgcn_cvt_pkrtz(                     \
                    __builtin_amdgcn_exp2f(a0_), __builtin_amdgcn_exp2f(a1_)); \
            }                                                                \
            W[kc_] = uu_.h8; }                                               \
        }while(0)

#define MFMA_T(BUF, W) do{                                                   \
        _Pragma("unroll")                                                    \
        for (int kc_ = 0; kc_ < 2; kc_++){                                   \
            half8 af_ = W[kc_];                                              \
            accs = __builtin_amdgcn_mfma_f32_16x16x32_f16(af_, ones, accs, 0, 0, 0); \
            _Pragma("unroll")                                                \
            for (int nt_ = 0; nt_ < 4; nt_++){                               \
                half8 bv_ = *(const half8*)&vtile[BUF][bbase + nt_ * 16 * 72 + kc_ * 32]; \
                acc[nt_] = __builtin_amdgcn_mfma_f32_16x16x32_f16(af_, bv_, acc[nt_], 0, 0, 0); \
            } } }while(0)

    // ---- prologue: tiles 0,1 in flight; tile 0 staged + A-frag computed
    LOADD(Ad); LOADV(Av0, Av1);
    LOADD(Bd); LOADV(Bv0, Bv1);
    STAGEV(0, Av0, Av1); WCOMP(WA, Ad);

    // ---- main: tiles (2jp, 2jp+1); 2-deep prefetch keeps 12 loads in flight
    for (int jp = 0; jp < 31; jp++){
        LOADD(Ad); LOADV(Av0, Av1);            // tile 2jp+2
        lds_barrier();                          // vtile0 (tile 2jp) visible
        MFMA_T(0, WA);                          // tile 2jp
        STAGEV(1, Bv0, Bv1); WCOMP(WB, Bd);     // tile 2jp+1
        LOADD(Bd); LOADV(Bv0, Bv1);            // tile 2jp+3
        lds_barrier();
        MFMA_T(1, WB);                          // tile 2jp+1
        STAGEV(0, Av0, Av1); WCOMP(WA, Ad);     // tile 2jp+2
    }
    // ---- tail: tiles 62, 63
    lds_barrier();
    MFMA_T(0, WA);                              // tile 62
    STAGEV(1, Bv0, Bv1); WCOMP(WB, Bd);         // tile 63
    lds_barrier();
    MFMA_T(1, WB);                              // tile 63

#undef LOADD
#undef LOADV
#undef STAGEV
#undef WCOMP
#undef MFMA_T

    // epilogue: D m=(lane>>4)*4+reg (i-local), n=lane&15 (bd); nt = batch b
    const int m0 = (lane >> 4) * 4;
    const int d  = lane & 15;
#pragma unroll
    for (int r4 = 0; r4 < 4; r4++){
        const int i = i0 + wv * 16 + m0 + r4;
        const float inv_s = 1.0f / fmaxf(accs[r4], 1e-30f);
#pragma unroll
        for (int nt = 0; nt < 4; nt++){
            float cc = acc[nt][r4] * inv_s;
            float g = 0.5f * cc * (1.0f + erff(cc * 0.70710678118654752f));
            out[((size_t)nt * NN + i) * (NH * NV) + h * NV + d] = g;
        }
    }
}

// ---------------------------------------------------------------------------
extern "C" void kernel_launch(void* const* d_in, const int* in_sizes, int n_in,
                              void* d_out, int out_size, void* d_ws, size_t ws_size,
                              hipStream_t stream) {
    const float* in   = (const float*)d_in[0]; // (B,N,C) f32
    const float* dist = (const float*)d_in[1]; // (N,N) f32
    const float* r    = (const float*)d_in[2]; // (H,1,1) f32
    const float* wgt  = (const float*)d_in[3]; // (H,C,V) f32
    const int*   loc  = (const int*)d_in[4];   // scalar int
    float* out = (float*)d_out;                // (B,N,H*V) f32

    float* Kval = (float*)d_ws;
    float* xmin = Kval + NN;
    _Float16* val_t = (_Float16*)((char*)d_ws + 2 * (size_t)NN * sizeof(float)); // 4 MB

    k_rowstats<<<NN, 256, 0, stream>>>(dist, loc, Kval, xmin);
    k_value<<<dim3(NN / 32, NB), 256, 0, stream>>>(in, wgt, val_t);
    k_att<<<dim3(NN / 64, NH), 256, 0, stream>>>(dist, r, val_t, Kval, xmin, out);
}

// Round 5
// 168.544 us; speedup vs baseline: 1.0939x; 1.0939x over previous
//
#include <hip/hip_runtime.h>
#include <hip/hip_bf16.h>
#include <math.h>

#define NN 4096
#define NC 128
#define NH 8
#define NV 16
#define NB 4
#define BD 64   // NB*NV

typedef _Float16 half8 __attribute__((ext_vector_type(8)));
typedef __fp16  fp16x2 __attribute__((ext_vector_type(2)));
typedef float floatx4 __attribute__((ext_vector_type(4)));

__device__ __forceinline__ int get_loc(const int* locp){
    int lr = locp[0];
    return (lr >= 0 && lr <= 100) ? lr : 64;
}
__device__ __forceinline__ float head_scale(const float* rr, int h){
    float ts = tanf(0.78539816339744831f * (1.0f + sinf(rr[h])));
    if (!(ts > 0.f)) ts = (ts == 0.f) ? 1e-20f : 1e20f;
    if (ts > 1e20f) ts = 1e20f;
    return ts;
}
// barrier that drains LDS only — leaves global loads (vmcnt) in flight.
__device__ __forceinline__ void lds_barrier(){
    __asm__ __volatile__("s_waitcnt lgkmcnt(0)\n\ts_barrier" ::: "memory");
}

// ---------------------------------------------------------------------------
// FUSED K1+K2: blockIdx.x < 512  -> k_value work (MFMA, no LDS)
//              blockIdx.x >= 512 -> k_rowstats work (row i = blockIdx.x-512)
// The two are independent (both only feed k_att), so fusing lets the
// MFMA-heavy value blocks overlap the latency-bound rowstats blocks
// instead of serializing on the stream.
// Branch is block-uniform -> __syncthreads inside rowstats branch is legal.
// ---------------------------------------------------------------------------
__global__ __launch_bounds__(256) void k_prep(const float* __restrict__ dist,
                                              const int* __restrict__ locp,
                                              const float* __restrict__ in,
                                              const float* __restrict__ wgt,
                                              float* __restrict__ Kval,
                                              float* __restrict__ xminp,
                                              _Float16* __restrict__ val_t){
    __shared__ unsigned int hist[4][256];
    __shared__ float cand[1024];
    __shared__ unsigned int cnt, selb_s, basec_s, xminu;

    const int t = threadIdx.x, lane = t & 63, wv = t >> 6;

    if (blockIdx.x < 512){
        // ---------------- value branch: val_t[h][bd][j] = in x wgt --------
        const int idx = blockIdx.x;
        const int b   = idx & 3;
        const int j0  = (idx >> 2) * 32;
        const int kl  = (lane >> 4) * 8;        // k-offset inside a K=32 chunk
        const int v   = lane & 15;

        // B-frags straight from global (wgt is 512 KB -> L2-resident).
        // Bf[nt][kc][u] = wgt[h][kc*32+kl+u][v], h = wv*2+nt.
        half8 Bf[2][4];
#pragma unroll
        for (int nt = 0; nt < 2; nt++){
            const int h = wv * 2 + nt;
            const float* wp = wgt + ((size_t)h * NC + kl) * NV + v;
#pragma unroll
            for (int kc = 0; kc < 4; kc++)
#pragma unroll
                for (int u = 0; u < 8; u++)
                    Bf[nt][kc][u] = (_Float16)wp[(kc * 32 + u) * NV];
        }

        floatx4 acc[2][2];
#pragma unroll
        for (int a = 0; a < 2; a++)
#pragma unroll
            for (int c = 0; c < 2; c++) acc[a][c] = (floatx4){0.f,0.f,0.f,0.f};

        const float* ip = in + ((size_t)b * NN + j0 + v) * NC + kl;
#pragma unroll
        for (int jm = 0; jm < 2; jm++){
            const float* ipm = ip + jm * 16 * NC;
#pragma unroll
            for (int kc = 0; kc < 4; kc++){
                float4 x0 = *(const float4*)(ipm + kc * 32);
                float4 x1 = *(const float4*)(ipm + kc * 32 + 4);
                const float xs[8] = {x0.x,x0.y,x0.z,x0.w,x1.x,x1.y,x1.z,x1.w};
                union { half8 h8; fp16x2 h2[4]; } hi, lo;
#pragma unroll
                for (int u = 0; u < 4; u++){
                    hi.h2[u] = __builtin_amdgcn_cvt_pkrtz(xs[2*u], xs[2*u+1]);
                    float r0 = xs[2*u]   - (float)hi.h2[u][0];
                    float r1 = xs[2*u+1] - (float)hi.h2[u][1];
                    lo.h2[u] = __builtin_amdgcn_cvt_pkrtz(r0, r1);
                }
#pragma unroll
                for (int nt = 0; nt < 2; nt++){
                    acc[jm][nt] = __builtin_amdgcn_mfma_f32_16x16x32_f16(hi.h8, Bf[nt][kc], acc[jm][nt], 0, 0, 0);
                    acc[jm][nt] = __builtin_amdgcn_mfma_f32_16x16x32_f16(lo.h8, Bf[nt][kc], acc[jm][nt], 0, 0, 0);
                }
            }
        }

        const int jw = (lane >> 4) * 4;
#pragma unroll
        for (int jm = 0; jm < 2; jm++)
#pragma unroll
            for (int nt = 0; nt < 2; nt++){
                const int h   = wv * 2 + nt;
                const int row = h * BD + b * NV + v;
                union { _Float16 hh[4]; uint2 u; } o;
#pragma unroll
                for (int u = 0; u < 4; u++) o.hh[u] = (_Float16)acc[jm][nt][u];
                *(uint2*)&val_t[(size_t)row * NN + j0 + jm * 16 + jw] = o.u;
            }
        return;
    }

    // ---------------- rowstats branch (unchanged algorithm) --------------
    const int i = blockIdx.x - 512;
    const int loc = get_loc(locp);
    const unsigned int rank = (unsigned int)(((long long)loc * (NN - 1)) / 100) + 1u;

    float v[16];
    const float4* rp = (const float4*)(dist + (size_t)i * NN);
#pragma unroll
    for (int k = 0; k < 4; k++){
        float4 x4 = rp[k * 256 + t];
        v[4*k+0] = x4.x; v[4*k+1] = x4.y; v[4*k+2] = x4.z; v[4*k+3] = x4.w;
    }
    for (int k = t; k < 1024; k += 256) ((unsigned int*)hist)[k] = 0;
    if (t == 0){ cnt = 0; selb_s = 255u; basec_s = 0u; xminu = 0xFFFFFFFFu; }
    __syncthreads();

    float lmin = 1e30f;
#pragma unroll
    for (int u = 0; u < 16; u++){
        float x = v[u];
        lmin = fminf(lmin, x);
        int b = (int)(x * 256.0f); b = b < 0 ? 0 : (b > 255 ? 255 : b);
        atomicAdd(&hist[wv][b], 1u);
    }
#pragma unroll
    for (int off = 1; off < 64; off <<= 1) lmin = fminf(lmin, __shfl_xor(lmin, off));
    if (lane == 0) atomicMin(&xminu, __float_as_uint(lmin));
    __syncthreads();

    if (t < 64){
        unsigned int lp[4];
        unsigned int run = 0;
#pragma unroll
        for (int q = 0; q < 4; q++){
            int b = 4 * t + q;
            run += hist[0][b] + hist[1][b] + hist[2][b] + hist[3][b];
            lp[q] = run;
        }
        unsigned int incl = run;
#pragma unroll
        for (int d = 1; d < 64; d <<= 1){
            unsigned int y = __shfl_up(incl, d);
            if (t >= d) incl += y;
        }
        unsigned int excl = incl - run;
        if (excl < rank && rank <= incl){
#pragma unroll
            for (int q = 0; q < 4; q++){
                if (excl + lp[q] >= rank){
                    selb_s  = (unsigned int)(4 * t + q);
                    basec_s = excl + (q ? lp[q-1] : 0u);
                    break;
                }
            }
        }
    }
    __syncthreads();
    const unsigned int sb = selb_s;
    if (t == 0) Kval[i] = ((float)sb + 1.0f) * 0.00390625f;   // fallback, overwritten below
#pragma unroll
    for (int u = 0; u < 16; u++){
        float x = v[u];
        int b = (int)(x * 256.0f); b = b < 0 ? 0 : (b > 255 ? 255 : b);
        if ((unsigned int)b == sb){
            unsigned int idx = atomicAdd(&cnt, 1u);
            if (idx < 1024u) cand[idx] = x;
        }
    }
    __syncthreads();
    const unsigned int n = cnt > 1024u ? 1024u : cnt;
    const unsigned int need = rank - basec_s;
    for (unsigned int c0 = t; c0 < n; c0 += 256){
        float x = cand[c0];
        unsigned int lt = 0, le = 0;
        for (unsigned int k2 = 0; k2 < n; k2++){
            float y = cand[k2];
            lt += (y < x); le += (y <= x);
        }
        if (lt < need && need <= le) Kval[i] = x;
    }
    if (t == 0) xminp[i] = __uint_as_float(xminu);
}

// ---------------------------------------------------------------------------
// K3 (MFMA, double-buffered) — REVERTED to the R2 structure (measured 64 us):
// 32-i tiles, grid (NN/32, NH) = 1024 blocks = 4 blocks/CU; the kernel is
// latency-bound, so block-level TLP dominates (the 512-block 64-i variant
// regressed to 79 us at 19.7% occupancy despite lower LDS traffic).
// ---------------------------------------------------------------------------
__global__ __launch_bounds__(256) void k_att(const float* __restrict__ dist,
                                             const float* __restrict__ rr,
                                             const _Float16* __restrict__ val_t,
                                             const float* __restrict__ Kvalp,
                                             const float* __restrict__ xminp,
                                             float* __restrict__ out){
    __shared__ alignas(16) _Float16 wtile[2][32 * 72];   // [i][j]  2 x 4.6 KB
    __shared__ alignas(16) _Float16 vtile[2][64 * 72];   // [bd][j] 2 x 9.2 KB

    // XCD remap: linear id l -> xcd = l&7 (round-robin dispatch), slot s.
    // Within an XCD, h varies fastest -> concurrent set = 4 i-tiles x 8 h.
    const int l   = blockIdx.x + (NN / 32) * blockIdx.y;   // 0..1023
    const int xcd = l & 7;
    const int s   = l >> 3;                                // 0..127
    const int i0  = (xcd * 16 + (s >> 3)) * 32;
    const int h   = s & 7;

    const int t = threadIdx.x;
    const int lane = t & 63, wv = t >> 6;
    const float ts  = head_scale(rr, h);
    const float ts2 = ts * 1.44269504088896f;   // exp(a) = exp2(a*log2e)

    // staging roles (fixed per thread)
    const int il = t >> 3, jq = t & 7;          // w-stage: row il, 8 j's
    const int vrow = t >> 3, vpart = t & 7;     // v-stage: rows vrow, vrow+32
    const float kvi  = Kvalp[i0 + il];
    const float txmi = ts2 * xminp[i0 + il];
    const float nts2 = -ts2;

    half8 ones;
#pragma unroll
    for (int u = 0; u < 8; u++) ones[u] = (_Float16)1.0f;

    const float* dp = dist + (size_t)(i0 + il) * NN + jq * 8;
    const _Float16* vp0 = val_t + (size_t)(h * BD + vrow) * NN + vpart * 8;
    const _Float16* vp1 = vp0 + (size_t)32 * NN;

    floatx4 acc0 = (floatx4){0.f,0.f,0.f,0.f};
    floatx4 acc1 = (floatx4){0.f,0.f,0.f,0.f};
    floatx4 accs = (floatx4){0.f,0.f,0.f,0.f};

    const int is16 = (wv & 1) * 16;
    const int bh   = (wv >> 1) * 32;
    const int aoff  = (is16 + (lane & 15)) * 72 + (lane >> 4) * 8;
    const int boff0 = (bh + (lane & 15)) * 72 + (lane >> 4) * 8;
    const int boff1 = boff0 + 16 * 72;
    const int voff0 = vrow * 72 + vpart * 8;
    const int voff1 = (vrow + 32) * 72 + vpart * 8;
    const int woff  = il * 72 + jq * 8;

    uint4  Av0, Av1, Bv0, Bv1;
    float4 Ad0, Ad1, Bd0, Bd1;

#define LOADSET(V0, V1, D0, D1) do{                                          \
        V0 = *(const uint4*)vp0;  vp0 += 64;                                 \
        V1 = *(const uint4*)vp1;  vp1 += 64;                                 \
        D0 = *(const float4*)dp;                                             \
        D1 = *(const float4*)(dp + 4);  dp += 64; }while(0)

#define STAGE(BUF, V0, V1, D0, D1) do{                                       \
        *(uint4*)&vtile[BUF][voff0] = V0;                                    \
        *(uint4*)&vtile[BUF][voff1] = V1;                                    \
        const float dd_[8] = {D0.x,D0.y,D0.z,D0.w,D1.x,D1.y,D1.z,D1.w};      \
        union { half8 h8; fp16x2 h2[4]; } uu_;                               \
        _Pragma("unroll")                                                    \
        for (int u_ = 0; u_ < 4; u_++){                                      \
            float a0_ = fmaf(nts2, dd_[2*u_  ], txmi);                       \
            float a1_ = fmaf(nts2, dd_[2*u_+1], txmi);                       \
            a0_ = (dd_[2*u_  ] <= kvi) ? a0_ : -20000.0f;                    \
            a1_ = (dd_[2*u_+1] <= kvi) ? a1_ : -20000.0f;                    \
            uu_.h2[u_] = __builtin_amdgcn_cvt_pkrtz(                         \
                __builtin_amdgcn_exp2f(a0_), __builtin_amdgcn_exp2f(a1_));   \
        }                                                                    \
        *(half8*)&wtile[BUF][woff] = uu_.h8; }while(0)

#define MFMA_T(BUF) do{                                                      \
        _Pragma("unroll")                                                    \
        for (int kc_ = 0; kc_ < 2; kc_++){                                   \
            half8 af = *(const half8*)&wtile[BUF][aoff  + kc_ * 32];         \
            half8 b0 = *(const half8*)&vtile[BUF][boff0 + kc_ * 32];         \
            half8 b1 = *(const half8*)&vtile[BUF][boff1 + kc_ * 32];         \
            acc0 = __builtin_amdgcn_mfma_f32_16x16x32_f16(af, b0, acc0, 0, 0, 0); \
            acc1 = __builtin_amdgcn_mfma_f32_16x16x32_f16(af, b1, acc1, 0, 0, 0); \
            accs = __builtin_amdgcn_mfma_f32_16x16x32_f16(af, ones, accs, 0, 0, 0); \
        } }while(0)

    // ---- prologue: t0 -> A, t1 -> B; stage t0 into buf0
    LOADSET(Av0, Av1, Ad0, Ad1);
    LOADSET(Bv0, Bv1, Bd0, Bd1);
    STAGE(0, Av0, Av1, Ad0, Ad1);

    // ---- main: tiles (2jp, 2jp+1); prefetch 2jp+2 -> A, 2jp+3 -> B.
    // One LDS-only barrier per tile; 2 register sets keep 8 global loads
    // in flight so staging never waits on a fresh load.
    for (int jp = 0; jp < 31; jp++){
        LOADSET(Av0, Av1, Ad0, Ad1);          // tile 2jp+2
        lds_barrier();
        MFMA_T(0);                             // tile 2jp   (buf0)
        STAGE(1, Bv0, Bv1, Bd0, Bd1);          // tile 2jp+1 -> buf1
        LOADSET(Bv0, Bv1, Bd0, Bd1);          // tile 2jp+3
        lds_barrier();
        MFMA_T(1);                             // tile 2jp+1 (buf1)
        STAGE(0, Av0, Av1, Ad0, Ad1);          // tile 2jp+2 -> buf0
    }
    // ---- tail: tiles 62 (buf0, already staged) and 63 (in B)
    lds_barrier();
    MFMA_T(0);                                 // tile 62
    STAGE(1, Bv0, Bv1, Bd0, Bd1);              // tile 63 -> buf1
    lds_barrier();
    MFMA_T(1);                                 // tile 63

#undef LOADSET
#undef STAGE
#undef MFMA_T

    // epilogue: D[m][n]: m=(lane>>4)*4+reg, n=lane&15; accs holds row-sums S
    const int m0 = (lane >> 4) * 4;
    const int d  = lane & 15;
#pragma unroll
    for (int r4 = 0; r4 < 4; r4++){
        const int iloc = is16 + m0 + r4;
        const float inv_s = 1.0f / fmaxf(accs[r4], 1e-30f);
#pragma unroll
        for (int nt = 0; nt < 2; nt++){
            const int b = (wv >> 1) * 2 + nt;
            float c = acc0[r4], c1 = acc1[r4];
            float cc = (nt == 0 ? c : c1) * inv_s;
            float g = 0.5f * cc * (1.0f + erff(cc * 0.70710678118654752f));
            out[((size_t)b * NN + i0 + iloc) * (NH * NV) + h * NV + d] = g;
        }
    }
}

// ---------------------------------------------------------------------------
extern "C" void kernel_launch(void* const* d_in, const int* in_sizes, int n_in,
                              void* d_out, int out_size, void* d_ws, size_t ws_size,
                              hipStream_t stream) {
    const float* in   = (const float*)d_in[0]; // (B,N,C) f32
    const float* dist = (const float*)d_in[1]; // (N,N) f32
    const float* r    = (const float*)d_in[2]; // (H,1,1) f32
    const float* wgt  = (const float*)d_in[3]; // (H,C,V) f32
    const int*   loc  = (const int*)d_in[4];   // scalar int
    float* out = (float*)d_out;                // (B,N,H*V) f32

    float* Kval = (float*)d_ws;
    float* xmin = Kval + NN;
    _Float16* val_t = (_Float16*)((char*)d_ws + 2 * (size_t)NN * sizeof(float)); // 4 MB

    k_prep<<<512 + NN, 256, 0, stream>>>(dist, loc, in, wgt, Kval, xmin, val_t);
    k_att<<<dim3(NN / 32, NH), 256, 0, stream>>>(dist, r, val_t, Kval, xmin, out);
}

// Round 6
// 158.656 us; speedup vs baseline: 1.1621x; 1.0623x over previous
//
#include <hip/hip_runtime.h>
#include <hip/hip_bf16.h>
#include <math.h>

#define NN 4096
#define NC 128
#define NH 8
#define NV 16
#define NB 4
#define BD 64   // NB*NV

typedef _Float16 half8 __attribute__((ext_vector_type(8)));
typedef __fp16  fp16x2 __attribute__((ext_vector_type(2)));
typedef float floatx4 __attribute__((ext_vector_type(4)));

__device__ __forceinline__ int get_loc(const int* locp){
    int lr = locp[0];
    return (lr >= 0 && lr <= 100) ? lr : 64;
}
__device__ __forceinline__ float head_scale(const float* rr, int h){
    float ts = tanf(0.78539816339744831f * (1.0f + sinf(rr[h])));
    if (!(ts > 0.f)) ts = (ts == 0.f) ? 1e-20f : 1e20f;
    if (ts > 1e20f) ts = 1e20f;
    return ts;
}
// barrier that drains LDS only — leaves global loads (vmcnt) in flight.
__device__ __forceinline__ void lds_barrier(){
    __asm__ __volatile__("s_waitcnt lgkmcnt(0)\n\ts_barrier" ::: "memory");
}

// ---------------------------------------------------------------------------
// FUSED K1+K2 (unchanged from R5 — passed): blockIdx.x < 512 -> value MFMA;
// else rowstats row i = blockIdx.x-512.
// ---------------------------------------------------------------------------
__global__ __launch_bounds__(256) void k_prep(const float* __restrict__ dist,
                                              const int* __restrict__ locp,
                                              const float* __restrict__ in,
                                              const float* __restrict__ wgt,
                                              float* __restrict__ Kval,
                                              float* __restrict__ xminp,
                                              _Float16* __restrict__ val_t){
    __shared__ unsigned int hist[4][256];
    __shared__ float cand[1024];
    __shared__ unsigned int cnt, selb_s, basec_s, xminu;

    const int t = threadIdx.x, lane = t & 63, wv = t >> 6;

    if (blockIdx.x < 512){
        // ---------------- value branch: val_t[h][bd][j] = in x wgt --------
        const int idx = blockIdx.x;
        const int b   = idx & 3;
        const int j0  = (idx >> 2) * 32;
        const int kl  = (lane >> 4) * 8;        // k-offset inside a K=32 chunk
        const int v   = lane & 15;

        // B-frags straight from global (wgt is 512 KB -> L2-resident).
        half8 Bf[2][4];
#pragma unroll
        for (int nt = 0; nt < 2; nt++){
            const int h = wv * 2 + nt;
            const float* wp = wgt + ((size_t)h * NC + kl) * NV + v;
#pragma unroll
            for (int kc = 0; kc < 4; kc++)
#pragma unroll
                for (int u = 0; u < 8; u++)
                    Bf[nt][kc][u] = (_Float16)wp[(kc * 32 + u) * NV];
        }

        floatx4 acc[2][2];
#pragma unroll
        for (int a = 0; a < 2; a++)
#pragma unroll
            for (int c = 0; c < 2; c++) acc[a][c] = (floatx4){0.f,0.f,0.f,0.f};

        const float* ip = in + ((size_t)b * NN + j0 + v) * NC + kl;
#pragma unroll
        for (int jm = 0; jm < 2; jm++){
            const float* ipm = ip + jm * 16 * NC;
#pragma unroll
            for (int kc = 0; kc < 4; kc++){
                float4 x0 = *(const float4*)(ipm + kc * 32);
                float4 x1 = *(const float4*)(ipm + kc * 32 + 4);
                const float xs[8] = {x0.x,x0.y,x0.z,x0.w,x1.x,x1.y,x1.z,x1.w};
                union { half8 h8; fp16x2 h2[4]; } hi, lo;
#pragma unroll
                for (int u = 0; u < 4; u++){
                    hi.h2[u] = __builtin_amdgcn_cvt_pkrtz(xs[2*u], xs[2*u+1]);
                    float r0 = xs[2*u]   - (float)hi.h2[u][0];
                    float r1 = xs[2*u+1] - (float)hi.h2[u][1];
                    lo.h2[u] = __builtin_amdgcn_cvt_pkrtz(r0, r1);
                }
#pragma unroll
                for (int nt = 0; nt < 2; nt++){
                    acc[jm][nt] = __builtin_amdgcn_mfma_f32_16x16x32_f16(hi.h8, Bf[nt][kc], acc[jm][nt], 0, 0, 0);
                    acc[jm][nt] = __builtin_amdgcn_mfma_f32_16x16x32_f16(lo.h8, Bf[nt][kc], acc[jm][nt], 0, 0, 0);
                }
            }
        }

        const int jw = (lane >> 4) * 4;
#pragma unroll
        for (int jm = 0; jm < 2; jm++)
#pragma unroll
            for (int nt = 0; nt < 2; nt++){
                const int h   = wv * 2 + nt;
                const int row = h * BD + b * NV + v;
                union { _Float16 hh[4]; uint2 u; } o;
#pragma unroll
                for (int u = 0; u < 4; u++) o.hh[u] = (_Float16)acc[jm][nt][u];
                *(uint2*)&val_t[(size_t)row * NN + j0 + jm * 16 + jw] = o.u;
            }
        return;
    }

    // ---------------- rowstats branch (unchanged algorithm) --------------
    const int i = blockIdx.x - 512;
    const int loc = get_loc(locp);
    const unsigned int rank = (unsigned int)(((long long)loc * (NN - 1)) / 100) + 1u;

    float v[16];
    const float4* rp = (const float4*)(dist + (size_t)i * NN);
#pragma unroll
    for (int k = 0; k < 4; k++){
        float4 x4 = rp[k * 256 + t];
        v[4*k+0] = x4.x; v[4*k+1] = x4.y; v[4*k+2] = x4.z; v[4*k+3] = x4.w;
    }
    for (int k = t; k < 1024; k += 256) ((unsigned int*)hist)[k] = 0;
    if (t == 0){ cnt = 0; selb_s = 255u; basec_s = 0u; xminu = 0xFFFFFFFFu; }
    __syncthreads();

    float lmin = 1e30f;
#pragma unroll
    for (int u = 0; u < 16; u++){
        float x = v[u];
        lmin = fminf(lmin, x);
        int b = (int)(x * 256.0f); b = b < 0 ? 0 : (b > 255 ? 255 : b);
        atomicAdd(&hist[wv][b], 1u);
    }
#pragma unroll
    for (int off = 1; off < 64; off <<= 1) lmin = fminf(lmin, __shfl_xor(lmin, off));
    if (lane == 0) atomicMin(&xminu, __float_as_uint(lmin));
    __syncthreads();

    if (t < 64){
        unsigned int lp[4];
        unsigned int run = 0;
#pragma unroll
        for (int q = 0; q < 4; q++){
            int b = 4 * t + q;
            run += hist[0][b] + hist[1][b] + hist[2][b] + hist[3][b];
            lp[q] = run;
        }
        unsigned int incl = run;
#pragma unroll
        for (int d = 1; d < 64; d <<= 1){
            unsigned int y = __shfl_up(incl, d);
            if (t >= d) incl += y;
        }
        unsigned int excl = incl - run;
        if (excl < rank && rank <= incl){
#pragma unroll
            for (int q = 0; q < 4; q++){
                if (excl + lp[q] >= rank){
                    selb_s  = (unsigned int)(4 * t + q);
                    basec_s = excl + (q ? lp[q-1] : 0u);
                    break;
                }
            }
        }
    }
    __syncthreads();
    const unsigned int sb = selb_s;
    if (t == 0) Kval[i] = ((float)sb + 1.0f) * 0.00390625f;   // fallback, overwritten below
#pragma unroll
    for (int u = 0; u < 16; u++){
        float x = v[u];
        int b = (int)(x * 256.0f); b = b < 0 ? 0 : (b > 255 ? 255 : b);
        if ((unsigned int)b == sb){
            unsigned int idx = atomicAdd(&cnt, 1u);
            if (idx < 1024u) cand[idx] = x;
        }
    }
    __syncthreads();
    const unsigned int n = cnt > 1024u ? 1024u : cnt;
    const unsigned int need = rank - basec_s;
    for (unsigned int c0 = t; c0 < n; c0 += 256){
        float x = cand[c0];
        unsigned int lt = 0, le = 0;
        for (unsigned int k2 = 0; k2 < n; k2++){
            float y = cand[k2];
            lt += (y < x); le += (y <= x);
        }
        if (lt < need && need <= le) Kval[i] = x;
    }
    if (t == 0) xminp[i] = __uint_as_float(xminu);
}

// ---------------------------------------------------------------------------
// K3 (MFMA): 64-i tiles x 512 THREADS (8 waves), grid 512 blocks.
// vs R5 (32i/256thr/1024blk): per-block val_t read (512 KB) now serves 64
// output rows -> val_t L2 traffic halves (512->256 MB); total L2 ~1GB->768MB
// (L2 floor ~30us of the 65us kernel).  Waves/CU stays 16 (2 blk x 8 wv) —
// the parallelism R3's 256-thr/64-i variant lost (that was the regression
// cause, not LDS traffic).  Wave wv: i-strip wv>>1, bd-half wv&1.
// Per-thread staging drops to 1 uint4 (v) + 1 half8 (w).
// ---------------------------------------------------------------------------
__global__ __launch_bounds__(512) void k_att(const float* __restrict__ dist,
                                             const float* __restrict__ rr,
                                             const _Float16* __restrict__ val_t,
                                             const float* __restrict__ Kvalp,
                                             const float* __restrict__ xminp,
                                             float* __restrict__ out){
    __shared__ alignas(16) _Float16 wtile[2][64 * 72];   // [i][j]  2 x 9.2 KB
    __shared__ alignas(16) _Float16 vtile[2][64 * 72];   // [bd][j] 2 x 9.2 KB

    // XCD remap: 512 blocks round-robin xcd = l&7; h fastest within an XCD.
    const int l   = blockIdx.x;                // 0..511
    const int xcd = l & 7;
    const int s   = l >> 3;                    // 0..63
    const int i0  = (xcd * 8 + (s >> 3)) * 64;
    const int h   = s & 7;

    const int t = threadIdx.x;
    const int lane = t & 63, wv = t >> 6;      // wv 0..7
    const float ts  = head_scale(rr, h);
    const float ts2 = ts * 1.44269504088896f;  // exp(a) = exp2(a*log2e)
    const float nts2 = -ts2;

    // staging roles (fixed per thread): 512 thr x 16B = one 64x64 f16 tile
    const int il = t >> 3, jq = t & 7;         // w-stage: row il (0..63), 8 j's
    const float kvi  = Kvalp[i0 + il];
    const float txmi = ts2 * xminp[i0 + il];

    const float* dp = dist + (size_t)(i0 + il) * NN + jq * 8;
    const _Float16* vp = val_t + (size_t)(h * BD + il) * NN + jq * 8;

    half8 ones;
#pragma unroll
    for (int u = 0; u < 8; u++) ones[u] = (_Float16)1.0f;

    floatx4 acc0 = (floatx4){0.f,0.f,0.f,0.f};
    floatx4 acc1 = (floatx4){0.f,0.f,0.f,0.f};
    floatx4 accs = (floatx4){0.f,0.f,0.f,0.f};

    const int iq16 = (wv >> 1) * 16;           // i-strip within the 64-i tile
    const int bh   = (wv & 1) * 32;            // bd-half
    const int aoff  = (iq16 + (lane & 15)) * 72 + (lane >> 4) * 8;
    const int boff0 = (bh + (lane & 15)) * 72 + (lane >> 4) * 8;
    const int boff1 = boff0 + 16 * 72;
    const int voff  = il * 72 + jq * 8;        // same slot for v and w staging
    const int woff  = voff;

    uint4  Av, Bv;
    float4 Ad0, Ad1, Bd0, Bd1;

#define LOADSET(V, D0, D1) do{                                               \
        V  = *(const uint4*)vp;  vp += 64;                                   \
        D0 = *(const float4*)dp;                                             \
        D1 = *(const float4*)(dp + 4);  dp += 64; }while(0)

#define STAGE(BUF, V, D0, D1) do{                                            \
        *(uint4*)&vtile[BUF][voff] = V;                                      \
        const float dd_[8] = {D0.x,D0.y,D0.z,D0.w,D1.x,D1.y,D1.z,D1.w};      \
        union { half8 h8; fp16x2 h2[4]; } uu_;                               \
        _Pragma("unroll")                                                    \
        for (int u_ = 0; u_ < 4; u_++){                                      \
            float a0_ = fmaf(nts2, dd_[2*u_  ], txmi);                       \
            float a1_ = fmaf(nts2, dd_[2*u_+1], txmi);                       \
            a0_ = (dd_[2*u_  ] <= kvi) ? a0_ : -20000.0f;                    \
            a1_ = (dd_[2*u_+1] <= kvi) ? a1_ : -20000.0f;                    \
            uu_.h2[u_] = __builtin_amdgcn_cvt_pkrtz(                         \
                __builtin_amdgcn_exp2f(a0_), __builtin_amdgcn_exp2f(a1_));   \
        }                                                                    \
        *(half8*)&wtile[BUF][woff] = uu_.h8; }while(0)

#define MFMA_T(BUF) do{                                                      \
        _Pragma("unroll")                                                    \
        for (int kc_ = 0; kc_ < 2; kc_++){                                   \
            half8 af = *(const half8*)&wtile[BUF][aoff  + kc_ * 32];         \
            half8 b0 = *(const half8*)&vtile[BUF][boff0 + kc_ * 32];         \
            half8 b1 = *(const half8*)&vtile[BUF][boff1 + kc_ * 32];         \
            acc0 = __builtin_amdgcn_mfma_f32_16x16x32_f16(af, b0, acc0, 0, 0, 0); \
            acc1 = __builtin_amdgcn_mfma_f32_16x16x32_f16(af, b1, acc1, 0, 0, 0); \
            accs = __builtin_amdgcn_mfma_f32_16x16x32_f16(af, ones, accs, 0, 0, 0); \
        } }while(0)

    // ---- prologue: t0 -> A, t1 -> B; stage t0 into buf0
    LOADSET(Av, Ad0, Ad1);
    LOADSET(Bv, Bd0, Bd1);
    STAGE(0, Av, Ad0, Ad1);

    // ---- main: tiles (2jp, 2jp+1); prefetch 2jp+2 -> A, 2jp+3 -> B.
    for (int jp = 0; jp < 31; jp++){
        LOADSET(Av, Ad0, Ad1);                // tile 2jp+2
        lds_barrier();
        MFMA_T(0);                             // tile 2jp   (buf0)
        STAGE(1, Bv, Bd0, Bd1);                // tile 2jp+1 -> buf1
        LOADSET(Bv, Bd0, Bd1);                // tile 2jp+3
        lds_barrier();
        MFMA_T(1);                             // tile 2jp+1 (buf1)
        STAGE(0, Av, Ad0, Ad1);                // tile 2jp+2 -> buf0
    }
    // ---- tail: tiles 62 (buf0, already staged) and 63 (in B)
    lds_barrier();
    MFMA_T(0);                                 // tile 62
    STAGE(1, Bv, Bd0, Bd1);                    // tile 63 -> buf1
    lds_barrier();
    MFMA_T(1);                                 // tile 63

#undef LOADSET
#undef STAGE
#undef MFMA_T

    // epilogue: D[m][n]: m=(lane>>4)*4+reg (i-local), n=lane&15 (bd-local)
    const int m0 = (lane >> 4) * 4;
    const int d  = lane & 15;
#pragma unroll
    for (int r4 = 0; r4 < 4; r4++){
        const int i = i0 + iq16 + m0 + r4;
        const float inv_s = 1.0f / fmaxf(accs[r4], 1e-30f);
#pragma unroll
        for (int nt = 0; nt < 2; nt++){
            const int b = (wv & 1) * 2 + nt;
            float c = acc0[r4], c1 = acc1[r4];
            float cc = (nt == 0 ? c : c1) * inv_s;
            float g = 0.5f * cc * (1.0f + erff(cc * 0.70710678118654752f));
            out[((size_t)b * NN + i) * (NH * NV) + h * NV + d] = g;
        }
    }
}

// ---------------------------------------------------------------------------
extern "C" void kernel_launch(void* const* d_in, const int* in_sizes, int n_in,
                              void* d_out, int out_size, void* d_ws, size_t ws_size,
                              hipStream_t stream) {
    const float* in   = (const float*)d_in[0]; // (B,N,C) f32
    const float* dist = (const float*)d_in[1]; // (N,N) f32
    const float* r    = (const float*)d_in[2]; // (H,1,1) f32
    const float* wgt  = (const float*)d_in[3]; // (H,C,V) f32
    const int*   loc  = (const int*)d_in[4];   // scalar int
    float* out = (float*)d_out;                // (B,N,H*V) f32

    float* Kval = (float*)d_ws;
    float* xmin = Kval + NN;
    _Float16* val_t = (_Float16*)((char*)d_ws + 2 * (size_t)NN * sizeof(float)); // 4 MB

    k_prep<<<512 + NN, 256, 0, stream>>>(dist, loc, in, wgt, Kval, xmin, val_t);
    k_att<<<512, 512, 0, stream>>>(dist, r, val_t, Kval, xmin, out);
}

// Round 7
// 155.042 us; speedup vs baseline: 1.1892x; 1.0233x over previous
//
#include <hip/hip_runtime.h>
#include <hip/hip_bf16.h>
#include <math.h>

#define NN 4096
#define NC 128
#define NH 8
#define NV 16
#define NB 4
#define BD 64   // NB*NV

typedef _Float16 half8 __attribute__((ext_vector_type(8)));
typedef __fp16  fp16x2 __attribute__((ext_vector_type(2)));
typedef float floatx4 __attribute__((ext_vector_type(4)));

__device__ __forceinline__ int get_loc(const int* locp){
    int lr = locp[0];
    return (lr >= 0 && lr <= 100) ? lr : 64;
}
__device__ __forceinline__ float head_scale(const float* rr, int h){
    float ts = tanf(0.78539816339744831f * (1.0f + sinf(rr[h])));
    if (!(ts > 0.f)) ts = (ts == 0.f) ? 1e-20f : 1e20f;
    if (ts > 1e20f) ts = 1e20f;
    return ts;
}
// barrier that drains LDS only — leaves global loads (vmcnt) in flight.
__device__ __forceinline__ void lds_barrier(){
    __asm__ __volatile__("s_waitcnt lgkmcnt(0)\n\ts_barrier" ::: "memory");
}

// ---------------------------------------------------------------------------
// FUSED K1+K2 (unchanged — passed R5/R6): blockIdx.x < 512 -> value MFMA;
// else rowstats row i = blockIdx.x-512.
// ---------------------------------------------------------------------------
__global__ __launch_bounds__(256) void k_prep(const float* __restrict__ dist,
                                              const int* __restrict__ locp,
                                              const float* __restrict__ in,
                                              const float* __restrict__ wgt,
                                              float* __restrict__ Kval,
                                              float* __restrict__ xminp,
                                              _Float16* __restrict__ val_t){
    __shared__ unsigned int hist[4][256];
    __shared__ float cand[1024];
    __shared__ unsigned int cnt, selb_s, basec_s, xminu;

    const int t = threadIdx.x, lane = t & 63, wv = t >> 6;

    if (blockIdx.x < 512){
        // ---------------- value branch: val_t[h][bd][j] = in x wgt --------
        const int idx = blockIdx.x;
        const int b   = idx & 3;
        const int j0  = (idx >> 2) * 32;
        const int kl  = (lane >> 4) * 8;        // k-offset inside a K=32 chunk
        const int v   = lane & 15;

        // B-frags straight from global (wgt is 512 KB -> L2-resident).
        half8 Bf[2][4];
#pragma unroll
        for (int nt = 0; nt < 2; nt++){
            const int h = wv * 2 + nt;
            const float* wp = wgt + ((size_t)h * NC + kl) * NV + v;
#pragma unroll
            for (int kc = 0; kc < 4; kc++)
#pragma unroll
                for (int u = 0; u < 8; u++)
                    Bf[nt][kc][u] = (_Float16)wp[(kc * 32 + u) * NV];
        }

        floatx4 acc[2][2];
#pragma unroll
        for (int a = 0; a < 2; a++)
#pragma unroll
            for (int c = 0; c < 2; c++) acc[a][c] = (floatx4){0.f,0.f,0.f,0.f};

        const float* ip = in + ((size_t)b * NN + j0 + v) * NC + kl;
#pragma unroll
        for (int jm = 0; jm < 2; jm++){
            const float* ipm = ip + jm * 16 * NC;
#pragma unroll
            for (int kc = 0; kc < 4; kc++){
                float4 x0 = *(const float4*)(ipm + kc * 32);
                float4 x1 = *(const float4*)(ipm + kc * 32 + 4);
                const float xs[8] = {x0.x,x0.y,x0.z,x0.w,x1.x,x1.y,x1.z,x1.w};
                union { half8 h8; fp16x2 h2[4]; } hi, lo;
#pragma unroll
                for (int u = 0; u < 4; u++){
                    hi.h2[u] = __builtin_amdgcn_cvt_pkrtz(xs[2*u], xs[2*u+1]);
                    float r0 = xs[2*u]   - (float)hi.h2[u][0];
                    float r1 = xs[2*u+1] - (float)hi.h2[u][1];
                    lo.h2[u] = __builtin_amdgcn_cvt_pkrtz(r0, r1);
                }
#pragma unroll
                for (int nt = 0; nt < 2; nt++){
                    acc[jm][nt] = __builtin_amdgcn_mfma_f32_16x16x32_f16(hi.h8, Bf[nt][kc], acc[jm][nt], 0, 0, 0);
                    acc[jm][nt] = __builtin_amdgcn_mfma_f32_16x16x32_f16(lo.h8, Bf[nt][kc], acc[jm][nt], 0, 0, 0);
                }
            }
        }

        const int jw = (lane >> 4) * 4;
#pragma unroll
        for (int jm = 0; jm < 2; jm++)
#pragma unroll
            for (int nt = 0; nt < 2; nt++){
                const int h   = wv * 2 + nt;
                const int row = h * BD + b * NV + v;
                union { _Float16 hh[4]; uint2 u; } o;
#pragma unroll
                for (int u = 0; u < 4; u++) o.hh[u] = (_Float16)acc[jm][nt][u];
                *(uint2*)&val_t[(size_t)row * NN + j0 + jm * 16 + jw] = o.u;
            }
        return;
    }

    // ---------------- rowstats branch (unchanged algorithm) --------------
    const int i = blockIdx.x - 512;
    const int loc = get_loc(locp);
    const unsigned int rank = (unsigned int)(((long long)loc * (NN - 1)) / 100) + 1u;

    float v[16];
    const float4* rp = (const float4*)(dist + (size_t)i * NN);
#pragma unroll
    for (int k = 0; k < 4; k++){
        float4 x4 = rp[k * 256 + t];
        v[4*k+0] = x4.x; v[4*k+1] = x4.y; v[4*k+2] = x4.z; v[4*k+3] = x4.w;
    }
    for (int k = t; k < 1024; k += 256) ((unsigned int*)hist)[k] = 0;
    if (t == 0){ cnt = 0; selb_s = 255u; basec_s = 0u; xminu = 0xFFFFFFFFu; }
    __syncthreads();

    float lmin = 1e30f;
#pragma unroll
    for (int u = 0; u < 16; u++){
        float x = v[u];
        lmin = fminf(lmin, x);
        int b = (int)(x * 256.0f); b = b < 0 ? 0 : (b > 255 ? 255 : b);
        atomicAdd(&hist[wv][b], 1u);
    }
#pragma unroll
    for (int off = 1; off < 64; off <<= 1) lmin = fminf(lmin, __shfl_xor(lmin, off));
    if (lane == 0) atomicMin(&xminu, __float_as_uint(lmin));
    __syncthreads();

    if (t < 64){
        unsigned int lp[4];
        unsigned int run = 0;
#pragma unroll
        for (int q = 0; q < 4; q++){
            int b = 4 * t + q;
            run += hist[0][b] + hist[1][b] + hist[2][b] + hist[3][b];
            lp[q] = run;
        }
        unsigned int incl = run;
#pragma unroll
        for (int d = 1; d < 64; d <<= 1){
            unsigned int y = __shfl_up(incl, d);
            if (t >= d) incl += y;
        }
        unsigned int excl = incl - run;
        if (excl < rank && rank <= incl){
#pragma unroll
            for (int q = 0; q < 4; q++){
                if (excl + lp[q] >= rank){
                    selb_s  = (unsigned int)(4 * t + q);
                    basec_s = excl + (q ? lp[q-1] : 0u);
                    break;
                }
            }
        }
    }
    __syncthreads();
    const unsigned int sb = selb_s;
    if (t == 0) Kval[i] = ((float)sb + 1.0f) * 0.00390625f;   // fallback, overwritten below
#pragma unroll
    for (int u = 0; u < 16; u++){
        float x = v[u];
        int b = (int)(x * 256.0f); b = b < 0 ? 0 : (b > 255 ? 255 : b);
        if ((unsigned int)b == sb){
            unsigned int idx = atomicAdd(&cnt, 1u);
            if (idx < 1024u) cand[idx] = x;
        }
    }
    __syncthreads();
    const unsigned int n = cnt > 1024u ? 1024u : cnt;
    const unsigned int need = rank - basec_s;
    for (unsigned int c0 = t; c0 < n; c0 += 256){
        float x = cand[c0];
        unsigned int lt = 0, le = 0;
        for (unsigned int k2 = 0; k2 < n; k2++){
            float y = cand[k2];
            lt += (y < x); le += (y <= x);
        }
        if (lt < need && need <= le) Kval[i] = x;
    }
    if (t == 0) xminp[i] = __uint_as_float(xminu);
}

// ---------------------------------------------------------------------------
// K3: 64i x 64bd x 512thr (8 waves), grid 512 — R6 structure, two changes:
// (1) K-SPLIT WAVE RE-TILE: wave = 32i x 32bd subtile x HALF the K range
//     (khalf = wv&1 -> j-offset khalf*32 in each 64j tile).  LDS reads/wave-
//     iter drop 6 -> 4 (reads scale as (M+N)*K; 32+32 at K/2 beats 16+32 at
//     K).  Block-iter read instrs 48 -> 32.  LDS was ~41us of the 56us
//     (one LDS unit/CU; 12cyc/b128).  K-half partials merged once via LDS.
// (2) unpadded [64][64] tiles + XOR swizzle (c8 ^= (row&7)<<3 on f16 idx)
//     replaces the 72-pad — kills the 6.3M bank-conflict cycles.
// Same MFMA intrinsic/fragment layout, same staging roles, same schedule.
// ---------------------------------------------------------------------------
__global__ __launch_bounds__(512) void k_att(const float* __restrict__ dist,
                                             const float* __restrict__ rr,
                                             const _Float16* __restrict__ val_t,
                                             const float* __restrict__ Kvalp,
                                             const float* __restrict__ xminp,
                                             float* __restrict__ out){
    __shared__ alignas(16) char lds_raw[32768];
    _Float16* wtile = (_Float16*)lds_raw;              // [2][4096] f16
    _Float16* vtile = (_Float16*)(lds_raw + 16384);    // [2][4096] f16
    float*    mrg   = (float*)lds_raw;                 // 24 KB, reused post-loop

    // XCD remap: h fastest within an XCD -> 8 h-blocks share dist rows in L2.
    const int l    = blockIdx.x;               // 0..511
    const int xcd  = l & 7;
    const int sblk = l >> 3;                   // 0..63
    const int i0   = (xcd * 8 + (sblk >> 3)) * 64;
    const int h    = sblk & 7;

    const int t = threadIdx.x;
    const int lane = t & 63, wv = t >> 6;      // wv 0..7
    const float ts  = head_scale(rr, h);
    const float ts2 = ts * 1.44269504088896f;  // exp(a) = exp2(a*log2e)
    const float nts2 = -ts2;

    // staging roles: thread t -> row il (0..63), 8-f16 chunk jq (0..7)
    const int il = t >> 3, jq = t & 7;
    const float kvi  = Kvalp[i0 + il];
    const float txmi = ts2 * xminp[i0 + il];

    const float* dp = dist + (size_t)(i0 + il) * NN + jq * 8;
    const _Float16* vp = val_t + (size_t)(h * BD + il) * NN + jq * 8;

    // swizzled staging index (f16 units): row*64 + (c8 ^ ((row&7)<<3))
    const int stg = il * 64 + ((jq * 8) ^ ((il & 7) << 3));

    // wave MFMA roles: subtile sub (ih32,bh32), K-half khalf
    const int sub   = wv >> 1;                 // 0..3
    const int khalf = wv & 1;
    const int ih32  = (sub >> 1) * 32;
    const int bh32  = (sub & 1) * 32;
    const int cf    = khalf * 32 + (lane >> 4) * 8;   // k-offset (f16) in 64j tile
    const int cswz  = (lane & 7) << 3;
    const int aoff0 = (ih32 +      (lane & 15)) * 64 + (cf ^ cswz);
    const int aoff1 = (ih32 + 16 + (lane & 15)) * 64 + (cf ^ cswz);
    const int boff0 = (bh32 +      (lane & 15)) * 64 + (cf ^ cswz);
    const int boff1 = (bh32 + 16 + (lane & 15)) * 64 + (cf ^ cswz);

    half8 ones;
#pragma unroll
    for (int u = 0; u < 8; u++) ones[u] = (_Float16)1.0f;

    floatx4 acc00 = (floatx4){0.f,0.f,0.f,0.f};
    floatx4 acc01 = (floatx4){0.f,0.f,0.f,0.f};
    floatx4 acc10 = (floatx4){0.f,0.f,0.f,0.f};
    floatx4 acc11 = (floatx4){0.f,0.f,0.f,0.f};
    floatx4 accs0 = (floatx4){0.f,0.f,0.f,0.f};
    floatx4 accs1 = (floatx4){0.f,0.f,0.f,0.f};

    uint4  Av, Bv;
    float4 Ad0, Ad1, Bd0, Bd1;

#define LOADSET(V, D0, D1) do{                                               \
        V  = *(const uint4*)vp;  vp += 64;                                   \
        D0 = *(const float4*)dp;                                             \
        D1 = *(const float4*)(dp + 4);  dp += 64; }while(0)

#define STAGE(BUF, V, D0, D1) do{                                            \
        *(uint4*)&vtile[(BUF) * 4096 + stg] = V;                             \
        const float dd_[8] = {D0.x,D0.y,D0.z,D0.w,D1.x,D1.y,D1.z,D1.w};      \
        union { half8 h8; fp16x2 h2[4]; } uu_;                               \
        _Pragma("unroll")                                                    \
        for (int u_ = 0; u_ < 4; u_++){                                      \
            float a0_ = fmaf(nts2, dd_[2*u_  ], txmi);                       \
            float a1_ = fmaf(nts2, dd_[2*u_+1], txmi);                       \
            a0_ = (dd_[2*u_  ] <= kvi) ? a0_ : -20000.0f;                    \
            a1_ = (dd_[2*u_+1] <= kvi) ? a1_ : -20000.0f;                    \
            uu_.h2[u_] = __builtin_amdgcn_cvt_pkrtz(                         \
                __builtin_amdgcn_exp2f(a0_), __builtin_amdgcn_exp2f(a1_));   \
        }                                                                    \
        *(half8*)&wtile[(BUF) * 4096 + stg] = uu_.h8; }while(0)

#define MFMA_T(BUF) do{                                                      \
        const int bb_ = (BUF) * 4096;                                        \
        half8 a0 = *(const half8*)&wtile[bb_ + aoff0];                       \
        half8 a1 = *(const half8*)&wtile[bb_ + aoff1];                       \
        half8 b0 = *(const half8*)&vtile[bb_ + boff0];                       \
        half8 b1 = *(const half8*)&vtile[bb_ + boff1];                       \
        acc00 = __builtin_amdgcn_mfma_f32_16x16x32_f16(a0, b0, acc00, 0, 0, 0); \
        acc01 = __builtin_amdgcn_mfma_f32_16x16x32_f16(a0, b1, acc01, 0, 0, 0); \
        acc10 = __builtin_amdgcn_mfma_f32_16x16x32_f16(a1, b0, acc10, 0, 0, 0); \
        acc11 = __builtin_amdgcn_mfma_f32_16x16x32_f16(a1, b1, acc11, 0, 0, 0); \
        accs0 = __builtin_amdgcn_mfma_f32_16x16x32_f16(a0, ones, accs0, 0, 0, 0); \
        accs1 = __builtin_amdgcn_mfma_f32_16x16x32_f16(a1, ones, accs1, 0, 0, 0); \
        }while(0)

    // ---- prologue: t0 -> A, t1 -> B; stage t0 into buf0
    LOADSET(Av, Ad0, Ad1);
    LOADSET(Bv, Bd0, Bd1);
    STAGE(0, Av, Ad0, Ad1);

    // ---- main: tiles (2jp, 2jp+1); prefetch 2jp+2 -> A, 2jp+3 -> B.
    for (int jp = 0; jp < 31; jp++){
        LOADSET(Av, Ad0, Ad1);                // tile 2jp+2
        lds_barrier();
        MFMA_T(0);                             // tile 2jp   (buf0)
        STAGE(1, Bv, Bd0, Bd1);                // tile 2jp+1 -> buf1
        LOADSET(Bv, Bd0, Bd1);                // tile 2jp+3
        lds_barrier();
        MFMA_T(1);                             // tile 2jp+1 (buf1)
        STAGE(0, Av, Ad0, Ad1);                // tile 2jp+2 -> buf0
    }
    // ---- tail: tiles 62 (buf0, already staged) and 63 (in B)
    lds_barrier();
    MFMA_T(0);                                 // tile 62
    STAGE(1, Bv, Bd0, Bd1);                    // tile 63 -> buf1
    lds_barrier();
    MFMA_T(1);                                 // tile 63

#undef LOADSET
#undef STAGE
#undef MFMA_T

    // ---- K-half merge: wave wv keeps iq=khalf, ships iq=1-khalf to partner
    // (wv^1).  Region wv: 64 lanes x 12 f32 = 3 KB; 8 regions = 24 KB.
    lds_barrier();                             // all MFMA reads done; LDS free
    {
        floatx4 w0, w1, w2;
        if (khalf == 0){ w0 = acc10; w1 = acc11; w2 = accs1; }
        else           { w0 = acc00; w1 = acc01; w2 = accs0; }
        const int mb = wv * 768 + lane * 12;
        *(floatx4*)&mrg[mb    ] = w0;
        *(floatx4*)&mrg[mb + 4] = w1;
        *(floatx4*)&mrg[mb + 8] = w2;
    }
    lds_barrier();
    {
        const int mb = (wv ^ 1) * 768 + lane * 12;
        floatx4 m0 = *(const floatx4*)&mrg[mb    ];
        floatx4 m1 = *(const floatx4*)&mrg[mb + 4];
        floatx4 m2 = *(const floatx4*)&mrg[mb + 8];
        if (khalf == 0){ acc00 += m0; acc01 += m1; accs0 += m2; }
        else           { acc10 += m0; acc11 += m1; accs1 += m2; }
    }

    // ---- epilogue: finalize iq=khalf rows: i = i0+ih32+khalf*16+m0+r4,
    // cols bd = bh32 + bq*16 + d -> b = (sub&1)*2+bq, v = d.
    const floatx4 A0 = (khalf == 0) ? acc00 : acc10;
    const floatx4 A1 = (khalf == 0) ? acc01 : acc11;
    const floatx4 S  = (khalf == 0) ? accs0 : accs1;
    const int m0i = (lane >> 4) * 4;
    const int d   = lane & 15;
#pragma unroll
    for (int r4 = 0; r4 < 4; r4++){
        const int i = i0 + ih32 + khalf * 16 + m0i + r4;
        const float inv_s = 1.0f / fmaxf(S[r4], 1e-30f);
#pragma unroll
        for (int bq = 0; bq < 2; bq++){
            const int b = (sub & 1) * 2 + bq;
            float cc = (bq == 0 ? A0[r4] : A1[r4]) * inv_s;
            float g = 0.5f * cc * (1.0f + erff(cc * 0.70710678118654752f));
            out[((size_t)b * NN + i) * (NH * NV) + h * NV + d] = g;
        }
    }
}

// ---------------------------------------------------------------------------
extern "C" void kernel_launch(void* const* d_in, const int* in_sizes, int n_in,
                              void* d_out, int out_size, void* d_ws, size_t ws_size,
                              hipStream_t stream) {
    const float* in   = (const float*)d_in[0]; // (B,N,C) f32
    const float* dist = (const float*)d_in[1]; // (N,N) f32
    const float* r    = (const float*)d_in[2]; // (H,1,1) f32
    const float* wgt  = (const float*)d_in[3]; // (H,C,V) f32
    const int*   loc  = (const int*)d_in[4];   // scalar int
    float* out = (float*)d_out;                // (B,N,H*V) f32

    float* Kval = (float*)d_ws;
    float* xmin = Kval + NN;
    _Float16* val_t = (_Float16*)((char*)d_ws + 2 * (size_t)NN * sizeof(float)); // 4 MB

    k_prep<<<512 + NN, 256, 0, stream>>>(dist, loc, in, wgt, Kval, xmin, val_t);
    k_att<<<512, 512, 0, stream>>>(dist, r, val_t, Kval, xmin, out);
}